// Round 16
// baseline (3588.956 us; speedup 1.0000x reference)
//
#include <hip/hip_runtime.h>
#include <math.h>

#define Bsz 64
#define Tsz 1024
#define Esz 300
#define Hsz 200
#define Gsz 800   // 4*H
#define NTOK (Bsz*Tsz)
#define WPAD 6400

// NOTE: macro params must not collide with float4 member names x/y/z/w
#define FMA4(A_, W_, H_) do { \
  (A_).x = fmaf((W_).x, (H_), (A_).x); \
  (A_).y = fmaf((W_).y, (H_), (A_).y); \
  (A_).z = fmaf((W_).z, (H_), (A_).z); \
  (A_).w = fmaf((W_).w, (H_), (A_).w); } while (0)

// LDS-only barrier: drains lgkmcnt (all cross-thread traffic is LDS) but
// leaves global weight-stream loads in flight across the barrier.
// No sched_barrier (m141: order-pinning poison). All post-barrier
// consumers are ds_reads, which cannot hoist above the "memory" clobber.
__device__ __forceinline__ void lds_barrier() {
  asm volatile("s_waitcnt lgkmcnt(0)" ::: "memory");
  __builtin_amdgcn_s_barrier();
}

// Gate-interleaved layout (validated r13/r14): f4 #u = (i,f,g,o) of unit u.

// ---------------- lengths ----------------
__global__ __launch_bounds__(256) void k_lengths(const void* __restrict__ mraw,
                                                 int* __restrict__ lens) {
  __shared__ int red[256];
  const unsigned char* mb = (const unsigned char*)mraw;
  const int isbool = (mb[1] != 0);
  int b = blockIdx.x, tid = threadIdx.x;
  int s = 0;
  if (isbool) {
    const unsigned char* row = mb + (size_t)b * Tsz;
    for (int i = tid; i < Tsz; i += 256) s += (row[i] != 0);
  } else {
    const int* row = (const int*)mraw + (size_t)b * Tsz;
    for (int i = tid; i < Tsz; i += 256) s += (row[i] != 0);
  }
  red[tid] = s; __syncthreads();
  for (int off = 128; off; off >>= 1) {
    if (tid < off) red[tid] += red[tid + off];
    __syncthreads();
  }
  if (tid == 0) lens[b] = red[0];
}

// ---------------- Whh transpose + gate interleave ----------------------
__global__ __launch_bounds__(256) void k_transpose(const float* __restrict__ Whh,
                                                   float* __restrict__ WhhT) {
  int idx = blockIdx.x * 256 + threadIdx.x;
  if (idx >= Gsz * Hsz) return;
  int r = idx / Hsz, j = idx - r * Hsz;
  int rp = 4 * (r % Hsz) + r / Hsz;
  WhhT[(size_t)j * Gsz + rp] = Whh[idx];
}

// ---------------- standalone input-projection GEMM (pre-chunk/fallback) -
#define BM 64
#define BN 160
#define BK 20
__global__ __launch_bounds__(256) void k_gemm(const int* __restrict__ x,
                                              const float* __restrict__ embed,
                                              const float* __restrict__ Wf,
                                              const float* __restrict__ biasf,
                                              const float* __restrict__ Wb_,
                                              const float* __restrict__ biasb,
                                              float* __restrict__ Pf,
                                              float* __restrict__ Pb,
                                              int t0f, int t0b, int tcShift) {
  __shared__ __align__(16) float As[BK][BM];
  __shared__ __align__(16) float Bs[BK][BN];
  __shared__ int toks[BM];
  const int revz = blockIdx.z;
  const float* __restrict__ W    = revz ? Wb_  : Wf;
  const float* __restrict__ bias = revz ? biasb : biasf;
  float* __restrict__ P          = revz ? Pb   : Pf;
  const int t0                   = revz ? t0b  : t0f;
  int tid = threadIdx.x;
  int n0 = blockIdx.x * BM;
  int j0 = blockIdx.y * BN;
  if (tid < BM) {
    int n = n0 + tid;
    toks[tid] = x[((n >> tcShift) << 10) + t0 + (n & ((1 << tcShift) - 1))];
  }
  float acc[8][5];
#pragma unroll
  for (int i = 0; i < 8; i++)
#pragma unroll
    for (int j = 0; j < 5; j++) acc[i][j] = 0.f;
  int rg = tid >> 5;
  int cg = tid & 31;
  for (int k0 = 0; k0 < Esz; k0 += BK) {
    __syncthreads();
    for (int idx = tid; idx < BM * 5; idx += 256) {
      int r = idx / 5, q = idx % 5;
      const float4 v = *reinterpret_cast<const float4*>(
          embed + (size_t)toks[r] * Esz + k0 + q * 4);
      As[q * 4 + 0][r] = v.x; As[q * 4 + 1][r] = v.y;
      As[q * 4 + 2][r] = v.z; As[q * 4 + 3][r] = v.w;
    }
    for (int idx = tid; idx < BN * 5; idx += 256) {
      int j = idx / 5, q = idx % 5;
      int colg = j0 + j;
      int srcRow = (colg & 3) * Hsz + (colg >> 2);
      const float4 v = *reinterpret_cast<const float4*>(
          W + (size_t)srcRow * Esz + k0 + q * 4);
      Bs[q * 4 + 0][j] = v.x; Bs[q * 4 + 1][j] = v.y;
      Bs[q * 4 + 2][j] = v.z; Bs[q * 4 + 3][j] = v.w;
    }
    __syncthreads();
#pragma unroll
    for (int kk = 0; kk < BK; ++kk) {
      float4 a0 = *reinterpret_cast<const float4*>(&As[kk][rg * 8]);
      float4 a1 = *reinterpret_cast<const float4*>(&As[kk][rg * 8 + 4]);
      float a[8] = {a0.x, a0.y, a0.z, a0.w, a1.x, a1.y, a1.z, a1.w};
      float bv[5];
#pragma unroll
      for (int j = 0; j < 5; j++) bv[j] = Bs[kk][cg + 32 * j];
#pragma unroll
      for (int i = 0; i < 8; i++)
#pragma unroll
        for (int j = 0; j < 5; j++) acc[i][j] = fmaf(a[i], bv[j], acc[i][j]);
    }
  }
#pragma unroll
  for (int j = 0; j < 5; j++) {
    int col = j0 + cg + 32 * j;
    float bb = bias[(col & 3) * Hsz + (col >> 2)];
#pragma unroll
    for (int i = 0; i < 8; i++) {
      int n = n0 + rg * 8 + i;
      P[(size_t)n * Gsz + col] = acc[i][j] + bb;
    }
  }
}

// ---------------- fused: LSTM(chunk i) || GEMM(chunk i+1) --------------
// LSTM path: slabs [0,40) VGPR, [40,56) LDS, [56,80) streamed via 8-deep
// CROSS-STEP mod-24 ring (192 KB/step). lds_barrier (lgkmcnt-only) lets
// the tail refills stay in flight through the reduce/activation phases.
#define BM2 128
__global__ __launch_bounds__(512, 2) void k_fused(
    const float* __restrict__ Pf, const float* __restrict__ Pb,
    const float* __restrict__ WhhTf, const float* __restrict__ WhhTb,
    const int* __restrict__ lens,
    const float* __restrict__ Wa, const float* __restrict__ Wb,
    float* __restrict__ hcF, float* __restrict__ hcB,
    float* __restrict__ zaf, float* __restrict__ zbf,
    float* __restrict__ zab, float* __restrict__ zbb,
    int t0f, int t0b, int TC, int tcShift, int init,
    const int* __restrict__ x, const float* __restrict__ embed,
    const float* __restrict__ Wihf, const float* __restrict__ bf,
    const float* __restrict__ Wihb, const float* __restrict__ bb_,
    float* __restrict__ PfN, float* __restrict__ PbN,
    int t0fN, int t0bN, int gemmValid) {
  __shared__ __align__(16) float h[Hsz];
  __shared__ __align__(16) float4 part[1000];   // [gk][200]
  __shared__ __align__(16) float4 wlds[8000];   // [16][500] resident weights
  __shared__ float redA[2][8], redB[2][8];
  int bid = blockIdx.x, tid = threadIdx.x;

  if (bid >= 128) {
    // ================= GEMM path (next chunk, both dirs) ================
    if (!gemmValid) return;
    float* As = reinterpret_cast<float*>(wlds);          // [20][128]
    float* Bs = As + BK * BM2;                           // [20][160]
    int*  toks = reinterpret_cast<int*>(Bs + BK * BN);   // [128]
    int gid = bid - 128;
    int dir = gid / 640;
    int rem = gid - dir * 640;
    int gy = rem / 128;
    int gx = rem - gy * 128;
    const float* __restrict__ W    = dir ? Wihb : Wihf;
    const float* __restrict__ bias = dir ? bb_  : bf;
    float* __restrict__ P          = dir ? PbN  : PfN;
    const int t0                   = dir ? t0bN : t0fN;
    int n0 = gx * BM2;
    int j0 = gy * BN;
    if (tid < BM2) {
      int n = n0 + tid;
      toks[tid] = x[((n >> tcShift) << 10) + t0 + (n & ((1 << tcShift) - 1))];
    }
    float acc[8][5];
#pragma unroll
    for (int i = 0; i < 8; i++)
#pragma unroll
      for (int j = 0; j < 5; j++) acc[i][j] = 0.f;
    int rg = tid >> 5;    // 0..15, 8 rows each
    int cg = tid & 31;
    for (int k0 = 0; k0 < Esz; k0 += BK) {
      __syncthreads();
      for (int idx = tid; idx < BM2 * 5; idx += 512) {
        int r = idx / 5, q = idx % 5;
        const float4 v = *reinterpret_cast<const float4*>(
            embed + (size_t)toks[r] * Esz + k0 + q * 4);
        As[(q * 4 + 0) * BM2 + r] = v.x; As[(q * 4 + 1) * BM2 + r] = v.y;
        As[(q * 4 + 2) * BM2 + r] = v.z; As[(q * 4 + 3) * BM2 + r] = v.w;
      }
      for (int idx = tid; idx < BN * 5; idx += 512) {
        int j = idx / 5, q = idx % 5;
        int colg = j0 + j;
        int srcRow = (colg & 3) * Hsz + (colg >> 2);
        const float4 v = *reinterpret_cast<const float4*>(
            W + (size_t)srcRow * Esz + k0 + q * 4);
        Bs[(q * 4 + 0) * BN + j] = v.x; Bs[(q * 4 + 1) * BN + j] = v.y;
        Bs[(q * 4 + 2) * BN + j] = v.z; Bs[(q * 4 + 3) * BN + j] = v.w;
      }
      __syncthreads();
#pragma unroll
      for (int kk = 0; kk < BK; ++kk) {
        float4 a0 = *reinterpret_cast<const float4*>(&As[kk * BM2 + rg * 8]);
        float4 a1 = *reinterpret_cast<const float4*>(&As[kk * BM2 + rg * 8 + 4]);
        float a[8] = {a0.x, a0.y, a0.z, a0.w, a1.x, a1.y, a1.z, a1.w};
        float bv[5];
#pragma unroll
        for (int j = 0; j < 5; j++) bv[j] = Bs[kk * BN + cg + 32 * j];
#pragma unroll
        for (int i = 0; i < 8; i++)
#pragma unroll
          for (int j = 0; j < 5; j++) acc[i][j] = fmaf(a[i], bv[j], acc[i][j]);
      }
    }
#pragma unroll
    for (int j = 0; j < 5; j++) {
      int col = j0 + cg + 32 * j;
      float bb = bias[(col & 3) * Hsz + (col >> 2)];
#pragma unroll
      for (int i = 0; i < 8; i++) {
        int n = n0 + rg * 8 + i;
        P[(size_t)n * Gsz + col] = acc[i][j] + bb;
      }
    }
    return;
  }

  // ================= LSTM path ================
  int rev = bid >> 6;
  int b = bid & 63;
  int len = lens[b];
  const float* P    = rev ? Pb : Pf;
  const float* WhhT = rev ? WhhTb : WhhTf;
  float* hcb = (rev ? hcB : hcF) + (size_t)b * 2 * Hsz;
  float* za  = rev ? zab : zaf;
  float* zb  = rev ? zbb : zbf;
  int t0 = rev ? t0b : t0f;
  float wa = 0.f, wb = 0.f, c0 = 0.f;
  if (tid < Hsz) {
    h[tid] = init ? 0.f : hcb[tid];
    c0     = init ? 0.f : hcb[Hsz + tid];
    int off = rev ? Hsz : 0;
    wa = Wa[off + tid]; wb = Wb[off + tid];
  }
  const int worker = (tid < 500);
  int col = 0, gk = 0;
  if (worker) { col = tid % 100; gk = tid / 100; }
  const int hbase = gk * 40;
  const float4* __restrict__ wp4 =
      reinterpret_cast<const float4*>(WhhT) + (size_t)hbase * 200 + 2 * col;

  // slabs [0,40) VGPR, [40,56) LDS, [56,80) streamed cross-step ring
  float4 wreg[40];
  float4 rbuf[8];
  if (worker) {
#pragma unroll
    for (int q = 0; q < 40; q++) wreg[q] = wp4[(q >> 1) * 200 + (q & 1)];
#pragma unroll
    for (int i = 0; i < 16; i++)
      wlds[i * 500 + tid] = wp4[((40 + i) >> 1) * 200 + ((40 + i) & 1)];
    // prologue: fill ring with slabs 56..63
#pragma unroll
    for (int q = 0; q < 8; q++)
      rbuf[q] = wp4[((56 + q) >> 1) * 200 + ((56 + q) & 1)];
  }
  __syncthreads();

  int lo = t0;
  int hi = t0 + TC; if (len < hi) hi = len;
  int nsteps = hi - lo; if (nsteps < 0) nsteps = 0;

  for (int s = 0; s < nsteps; ++s) {
    int t = rev ? (hi - 1 - s) : (lo + s);
    const float4* __restrict__ Prow4 = reinterpret_cast<const float4*>(
        P + ((size_t)b * TC + (t - t0)) * Gsz);
    if (worker) {
      float4 acc0, acc1;
      if (gk == 0) { acc0 = Prow4[2 * col]; acc1 = Prow4[2 * col + 1]; }
      else {
        acc0.x = acc0.y = acc0.z = acc0.w = 0.f;
        acc1.x = acc1.y = acc1.z = acc1.w = 0.f;
      }
      // phase 1: VGPR-resident slabs [0,40)
#pragma unroll
      for (int u = 0; u < 20; u++) {
        float hj = h[hbase + u];
        FMA4(acc0, wreg[2 * u], hj);
        FMA4(acc1, wreg[2 * u + 1], hj);
      }
      // phase 2: LDS-resident slabs [40,56)
#pragma unroll
      for (int i = 0; i < 16; i++) {
        float hj = h[hbase + 20 + (i >> 1)];
        float4 wv = wlds[i * 500 + tid];
        if (i & 1) { FMA4(acc1, wv, hj); } else { FMA4(acc0, wv, hj); }
      }
      // phase 3: streamed slabs [56,80), cross-step mod-24 ring.
      // Refills for q>=16 are next step's slabs 56..63; with lds_barrier
      // they stay in flight through the tail.
#pragma unroll
      for (int q = 0; q < 24; q++) {
        float4 wv = rbuf[q & 7];
        const int r = 56 + ((q + 8) % 24);
        rbuf[q & 7] = wp4[(r >> 1) * 200 + (r & 1)];
        float hj = h[hbase + 28 + (q >> 1)];
        if (q & 1) { FMA4(acc1, wv, hj); } else { FMA4(acc0, wv, hj); }
      }
      part[gk * 200 + 2 * col]     = acc0;
      part[gk * 200 + 2 * col + 1] = acc1;
    }
    lds_barrier();   // bar A: partials visible; stream loads stay in flight
    float pa = 0.f, pb = 0.f;
    if (tid < Hsz) {
      float4 p0 = part[tid],       p1 = part[200 + tid], p2 = part[400 + tid];
      float4 p3 = part[600 + tid], p4 = part[800 + tid];
      float gi = p0.x + p1.x + p2.x + p3.x + p4.x;
      float gf = p0.y + p1.y + p2.y + p3.y + p4.y;
      float gc = p0.z + p1.z + p2.z + p3.z + p4.z;
      float go = p0.w + p1.w + p2.w + p3.w + p4.w;
      float ig = 1.f / (1.f + expf(-gi));
      float fg = 1.f / (1.f + expf(-gf));
      float gt = tanhf(gc);
      float og = 1.f / (1.f + expf(-go));
      float cn = fmaf(fg, c0, ig * gt);
      float hn = og * tanhf(cn);
      c0 = cn; h[tid] = hn;
      pa = hn * wa; pb = hn * wb;
    }
#pragma unroll
    for (int off = 32; off; off >>= 1) {
      pa += __shfl_down(pa, off);
      pb += __shfl_down(pb, off);
    }
    if ((tid & 63) == 0) { redA[s & 1][tid >> 6] = pa; redB[s & 1][tid >> 6] = pb; }
    lds_barrier();   // bar B: h + red visible for next step
    if (tid == 0) {
      float sa = 0.f, sb = 0.f;
#pragma unroll
      for (int w = 0; w < 8; ++w) { sa += redA[s & 1][w]; sb += redB[s & 1][w]; }
      za[(size_t)b * Tsz + t] = sa;
      zb[(size_t)b * Tsz + t] = sb;
    }
  }
  if (tid < Hsz) { hcb[tid] = h[tid]; hcb[Hsz + tid] = c0; }
}

// ---------------- Kuma head per token (double precision) ---------------
__global__ __launch_bounds__(256) void k_head(const float* __restrict__ zaf,
                                              const float* __restrict__ zbf,
                                              const float* __restrict__ zab,
                                              const float* __restrict__ zbb,
                                              const int* __restrict__ lens,
                                              const float* __restrict__ ba,
                                              const float* __restrict__ bb,
                                              float* __restrict__ zp) {
  int n = blockIdx.x * 256 + threadIdx.x;
  if (n >= NTOK) return;
  int b = n >> 10, t = n & 1023;
  if (t >= lens[b]) { zp[n] = 0.f; return; }
  double av = ((double)zaf[n] + (double)zab[n]) * 100.0 + (double)ba[0];
  double bv = ((double)zbf[n] + (double)zbb[n]) * 100.0 + (double)bb[0];
  double a  = av > 0.0 ? av + log1p(exp(-av)) : log1p(exp(av));
  double bk = bv > 0.0 ? bv + log1p(exp(-bv)) : log1p(exp(bv));
  a  = fmin(fmax(a, 1e-6), 100.0);
  bk = fmin(fmax(bk, 1e-6), 100.0);
  double ia = 1.0 + 1.0 / a;
  double lb = lgamma(ia) + lgamma(bk) - lgamma(ia + bk);
  double mean = bk * exp(lb);
  mean = -0.1 + 1.2 * mean;
  mean = fmin(fmax(mean, 0.0), 1.0);
  zp[n] = (float)mean;
}

// ---------------- stable top-k selection per row -----------------------
__global__ __launch_bounds__(256) void k_select(const float* __restrict__ zp,
                                                const int* __restrict__ lens,
                                                float* __restrict__ out) {
  __shared__ float zv[Tsz];
  __shared__ float wbv[4];
  __shared__ int wbi[4];
  __shared__ int stop;
  int b = blockIdx.x, tid = threadIdx.x;
  const float* row = zp + (size_t)b * Tsz;
  for (int i = tid; i < Tsz; i += 256) zv[i] = row[i];
  if (tid == 0) stop = 0;
  int len = lens[b];
  int k = (int)rintf(0.1f * (float)len);
  __syncthreads();
  for (int it = 0; it < k; ++it) {
    float bvl = -1.f; int bil = 0;
#pragma unroll
    for (int s = 0; s < 4; s++) {
      int i = tid * 4 + s;
      float v = zv[i];
      if (v > bvl) { bvl = v; bil = i; }
    }
    for (int off = 32; off; off >>= 1) {
      float ov = __shfl_down(bvl, off);
      int   oi = __shfl_down(bil, off);
      if (ov > bvl || (ov == bvl && oi < bil)) { bvl = ov; bil = oi; }
    }
    int w = tid >> 6;
    if ((tid & 63) == 0) { wbv[w] = bvl; wbi[w] = bil; }
    __syncthreads();
    if (tid == 0) {
      float fb = wbv[0]; int fi = wbi[0];
      for (int q = 1; q < 4; q++)
        if (wbv[q] > fb || (wbv[q] == fb && wbi[q] < fi)) { fb = wbv[q]; fi = wbi[q]; }
      if (fb <= 0.f) stop = 1;
      else { out[(size_t)b * Tsz + fi] = 1.0f; zv[fi] = -1e30f; }
    }
    __syncthreads();
    if (stop) break;
  }
}

extern "C" void kernel_launch(void* const* d_in, const int* in_sizes, int n_in,
                              void* d_out, int out_size, void* d_ws, size_t ws_size,
                              hipStream_t stream) {
  const int*   x      = (const int*)d_in[0];
  const void*  mask   = d_in[1];
  const float* embed  = (const float*)d_in[2];
  const float* Wih_f  = (const float*)d_in[3];
  const float* Whh_f  = (const float*)d_in[4];
  const float* b_f    = (const float*)d_in[5];
  const float* Wih_b  = (const float*)d_in[6];
  const float* Whh_b  = (const float*)d_in[7];
  const float* b_b    = (const float*)d_in[8];
  const float* Wa     = (const float*)d_in[9];
  const float* ba     = (const float*)d_in[10];
  const float* Wb     = (const float*)d_in[11];
  const float* bb     = (const float*)d_in[12];
  float* out = (float*)d_out;

  size_t fixedBytes = (5 * (size_t)NTOK + 2 * (size_t)Bsz * 2 * Hsz +
                       2 * ((size_t)Hsz * Gsz + WPAD)) * sizeof(float) +
                      Bsz * sizeof(int) + 1024;
  const int TCo = 256;
  size_t chunkFlO = (size_t)Bsz * TCo * Gsz;
  size_t needOverlap = fixedBytes + 4 * chunkFlO * sizeof(float);
  int overlap = (ws_size >= needOverlap);

  int TC = TCo, tcShift = 8, nP = 4;
  if (!overlap) {
    const int cand[5] = {256, 128, 64, 32, 16};
    for (int i = 0; i < 5; i++) {
      size_t need = fixedBytes + 2 * (size_t)Bsz * cand[i] * Gsz * sizeof(float);
      if (need <= ws_size) { TC = cand[i]; break; }
    }
    tcShift = 31 - __builtin_clz((unsigned)TC);
    nP = 2;
  }
  size_t chunkFl = (size_t)Bsz * TC * Gsz;

  float* Pbase = (float*)d_ws;
  float* PfA[2], *PbA[2];
  if (overlap) {
    PfA[0] = Pbase;               PfA[1] = Pbase + chunkFl;
    PbA[0] = Pbase + 2 * chunkFl; PbA[1] = Pbase + 3 * chunkFl;
  } else {
    PfA[0] = PfA[1] = Pbase;
    PbA[0] = PbA[1] = Pbase + chunkFl;
  }
  float* rest  = Pbase + nP * chunkFl;
  float* zaf   = rest;
  float* zbf   = zaf + NTOK;
  float* zab   = zbf + NTOK;
  float* zbb   = zab + NTOK;
  float* zp    = zbb + NTOK;
  float* hcF   = zp + NTOK;
  float* hcB   = hcF + (size_t)Bsz * 2 * Hsz;
  float* WhhTf = hcB + (size_t)Bsz * 2 * Hsz;
  float* WhhTb = WhhTf + (size_t)Hsz * Gsz + WPAD;
  int*   lens  = (int*)(WhhTb + (size_t)Hsz * Gsz + WPAD);

  k_lengths<<<Bsz, 256, 0, stream>>>(mask, lens);
  const int tgrid = (Gsz * Hsz + 255) / 256;
  k_transpose<<<tgrid, 256, 0, stream>>>(Whh_f, WhhTf);
  k_transpose<<<tgrid, 256, 0, stream>>>(Whh_b, WhhTb);

  int nch = Tsz / TC;
  if (overlap) {
    dim3 gg((Bsz * TC) / BM, Gsz / BN, 2);
    k_gemm<<<gg, 256, 0, stream>>>(x, embed, Wih_f, b_f, Wih_b, b_b,
                                   PfA[0], PbA[0], 0, (nch - 1) * TC, tcShift);
    for (int i = 0; i < nch; ++i) {
      int gv = (i < nch - 1);
      int grid = 128 + (gv ? 1280 : 0);
      k_fused<<<grid, 512, 0, stream>>>(
          PfA[i & 1], PbA[i & 1], WhhTf, WhhTb, lens, Wa, Wb, hcF, hcB,
          zaf, zbf, zab, zbb, i * TC, (nch - 1 - i) * TC, TC, tcShift, i == 0,
          x, embed, Wih_f, b_f, Wih_b, b_b,
          PfA[(i + 1) & 1], PbA[(i + 1) & 1],
          (i + 1) * TC, (nch - 2 - i) * TC, gv);
    }
  } else {
    dim3 gg((Bsz * TC) / BM, Gsz / BN, 2);
    for (int i = 0; i < nch; ++i) {
      k_gemm<<<gg, 256, 0, stream>>>(x, embed, Wih_f, b_f, Wih_b, b_b,
                                     PfA[0], PbA[0], i * TC,
                                     (nch - 1 - i) * TC, tcShift);
      k_fused<<<128, 512, 0, stream>>>(
          PfA[0], PbA[0], WhhTf, WhhTb, lens, Wa, Wb, hcF, hcB,
          zaf, zbf, zab, zbb, i * TC, (nch - 1 - i) * TC, TC, tcShift, i == 0,
          x, embed, Wih_f, b_f, Wih_b, b_b, PfA[0], PbA[0], 0, 0, 0);
    }
  }

  k_head<<<NTOK / 256, 256, 0, stream>>>(zaf, zbf, zab, zbb, lens, ba, bb, zp);

  (void)hipMemsetAsync(d_out, 0, (size_t)out_size * sizeof(float), stream);
  k_select<<<Bsz, 256, 0, stream>>>(zp, lens, out);
}